// Round 6
// baseline (593.818 us; speedup 1.0000x reference)
//
#include <hip/hip_runtime.h>
#include <hip/hip_cooperative_groups.h>
#include <stdint.h>

namespace cg = cooperative_groups;

// Problem constants (fixed by the reference):
#define NB 4
#define NN 50000
#define NE 800000
#define NF 128

#define GRID  512            // 2 blocks/CU on 256 CUs -> generous co-residency margin
#define NTHR  256
#define GSTR  (GRID * NTHR)
#define NTILE 1563           // ceil(NB*NN / 128) GEMM row tiles
#define NSBLK 196            // ceil(NN / 256) scan blocks (256 nodes each)
#define LDW   136            // W-LDS / epilogue-tile row stride in bf16 (128 + 8 pad)

typedef __attribute__((ext_vector_type(8))) short  bfrag;    // 8 bf16 (4 VGPR)
typedef __attribute__((ext_vector_type(4))) float  ffrag;    // 4 fp32 acc
typedef __attribute__((ext_vector_type(4))) short  short4v;  // 8 B LDS store

// fp32 -> bf16 round-to-nearest-even
__device__ inline unsigned short f2bf(float f) {
    unsigned int u = __builtin_bit_cast(unsigned int, f);
    u += 0x7fffu + ((u >> 16) & 1u);
    return (unsigned short)(u >> 16);
}
__device__ inline float bflo(unsigned int u) { return __builtin_bit_cast(float, u << 16); }
__device__ inline float bfhi(unsigned int u) { return __builtin_bit_cast(float, u & 0xffff0000u); }

// ---------------------------------------------------------------------------
// Shared GEMM tile body (used by both the cooperative front and the fallback
// gemm kernel).  Computes one 128-row tile t: h rows = bf16(x @ W^T), with W
// already staged in wsh as bf16.  No barriers inside the K-loop.
// ---------------------------------------------------------------------------
__device__ __forceinline__ void gemm_tile(
    const float* __restrict__ x, unsigned short* __restrict__ h,
    short* wsh, int t, int M, int tid)
{
    const int w    = tid >> 6;
    const int lane = tid & 63;
    const int q    = lane >> 4;
    const int l15  = lane & 15;
    const int r0   = t * 128 + w * 32;

    const float* xp[2];
#pragma unroll
    for (int i = 0; i < 2; ++i) {
        int gr = r0 + i * 16 + l15;
        gr = gr < M ? gr : M - 1;       // clamp: OOB rows computed, never stored
        xp[i] = x + (size_t)gr * NF + q * 8;
    }

    ffrag acc[2][8];
#pragma unroll
    for (int i = 0; i < 2; ++i)
#pragma unroll
        for (int j = 0; j < 8; ++j) acc[i][j] = (ffrag)0.f;

#pragma unroll 2
    for (int kc = 0; kc < 4; ++kc) {    // K-chunks of 32; NO barriers inside
        bfrag a[2];
#pragma unroll
        for (int i = 0; i < 2; ++i) {
            float4 u0 = *(const float4*)(xp[i] + kc * 32);
            float4 u1 = *(const float4*)(xp[i] + kc * 32 + 4);
            bfrag tt;
            tt[0] = (short)f2bf(u0.x); tt[1] = (short)f2bf(u0.y);
            tt[2] = (short)f2bf(u0.z); tt[3] = (short)f2bf(u0.w);
            tt[4] = (short)f2bf(u1.x); tt[5] = (short)f2bf(u1.y);
            tt[6] = (short)f2bf(u1.z); tt[7] = (short)f2bf(u1.w);
            a[i] = tt;
        }
#pragma unroll
        for (int j = 0; j < 8; ++j) {
            bfrag b = *(const bfrag*)&wsh[(j * 16 + l15) * LDW + kc * 32 + q * 8];
            acc[0][j] = __builtin_amdgcn_mfma_f32_16x16x32_bf16(
                a[0], b, acc[0][j], 0, 0, 0);
            acc[1][j] = __builtin_amdgcn_mfma_f32_16x16x32_bf16(
                a[1], b, acc[1][j], 0, 0, 0);
        }
    }

    // epilogue: repack through LDS (reuses wsh), coalesced 16 B stores
    __syncthreads();
    short* tile = wsh;
#pragma unroll
    for (int i = 0; i < 2; ++i)
#pragma unroll
        for (int reg = 0; reg < 4; ++reg) {
            int row = w * 32 + i * 16 + q * 4 + reg;
#pragma unroll
            for (int j = 0; j < 8; ++j)
                tile[row * LDW + j * 16 + l15] = (short)f2bf(acc[i][j][reg]);
        }
    __syncthreads();
#pragma unroll
    for (int it = 0; it < 8; ++it) {
        int row = it * 16 + (tid >> 4);
        int m   = t * 128 + row;
        if (m < M) {
            int n  = m % NN;
            int bb = m / NN;
            uint4 v = *(const uint4*)&tile[row * LDW + (tid & 15) * 8];
            *(uint4*)(h + ((size_t)n * NB + bb) * NF + (tid & 15) * 8) = v;
        }
    }
}

__device__ __forceinline__ void stage_W(const float* __restrict__ W,
                                        short* wsh, int tid)
{
#pragma unroll
    for (int it = 0; it < 16; ++it) {
        int idx = it * 256 + tid;       // float4 slot 0..4095
        int r   = idx >> 5;
        int c4  = idx & 31;
        float4 wv = *(const float4*)(W + (size_t)r * NF + c4 * 4);
        short4v wsv;
        wsv[0] = (short)f2bf(wv.x); wsv[1] = (short)f2bf(wv.y);
        wsv[2] = (short)f2bf(wv.z); wsv[3] = (short)f2bf(wv.w);
        *(short4v*)&wsh[r * LDW + c4 * 4] = wsv;
    }
}

// ---------------------------------------------------------------------------
// Cooperative front pipeline, ONE dispatch:
//   P0 zero cnt -> P1 histogram + GEMM -> P2 CSR scan -> P3 scatter.
// GRID=512 (2 blocks/CU; LDS 69.6 KB/CU, far under the 160 KB cap) for
// co-residency margin.  All access patterns are the R3-proven ones.
// ---------------------------------------------------------------------------
__global__ __launch_bounds__(256, 2) void front_kernel(
    const float* __restrict__ x,        // [M][NF] fp32
    const float* __restrict__ W,        // [NF][NF] fp32 (row = out feature)
    unsigned short* __restrict__ h,     // [NN][NB][NF] bf16, node-major
    const int* __restrict__ erow,
    const int* __restrict__ ecol,
    const float* __restrict__ ev,
    int* __restrict__ rs,               // [NN] block-local exclusive offsets
    int* __restrict__ cnt,              // [NN] histogram (consumed by scatter)
    int* __restrict__ bsum,             // [NSBLK] scan-block offsets
    uint2* __restrict__ cv_s)           // [NE] packed (col, val), row-sorted
{
    __shared__ short wsh[128 * LDW];    // 34.8 KB: W bf16 / epilogue tile / scan
    int* iw = (int*)wsh;

    const int tid  = threadIdx.x;
    const int gid  = blockIdx.x * NTHR + tid;
    const int w    = tid >> 6;
    const int lane = tid & 63;
    const int M    = NB * NN;
    cg::grid_group grid = cg::this_grid();

    // ---- P0: zero the histogram (replaces host memset) ----
    for (int i = gid; i < NN; i += GSTR) cnt[i] = 0;
    grid.sync();

    // ---- P1a: histogram (fire-and-forget atomics, drain under the GEMM) ----
    for (int e = gid; e < NE; e += GSTR)
        atomicAdd(&cnt[erow[e]], 1);

    // ---- P1b: GEMM tiles, grid-strided (W re-staged per tile; L2-hot) ----
    for (int t = blockIdx.x; t < NTILE; t += GRID) {
        __syncthreads();                // LDS reuse guard across tiles
        stage_W(W, wsh, tid);
        __syncthreads();
        gemm_tile(x, h, wsh, t, M, tid);
    }
    grid.sync();                        // hist atomics + all h stores complete

    // ---- P2a: coalesced block-local exclusive scan (1 elem/thread) ----
    if (blockIdx.x < NSBLK) {
        int i = blockIdx.x * 256 + tid;
        int v = (i < NN) ? cnt[i] : 0;
        int incl = v;
#pragma unroll
        for (int off = 1; off < 64; off <<= 1) {
            int tshf = __shfl_up(incl, off, 64);
            if (lane >= off) incl += tshf;
        }
        if (lane == 63) iw[w] = incl;
        __syncthreads();
        int woff = 0;
        for (int ww = 0; ww < w; ++ww) woff += iw[ww];
        if (i < NN) rs[i] = woff + incl - v;
        if (tid == 255) bsum[blockIdx.x] = woff + incl;   // block total
    }
    grid.sync();

    // ---- P2b: exclusive scan of the 196 block sums (block 0) ----
    if (blockIdx.x == 0) {
        int v = (tid < NSBLK) ? bsum[tid] : 0;
        int incl = v;
#pragma unroll
        for (int off = 1; off < 64; off <<= 1) {
            int tshf = __shfl_up(incl, off, 64);
            if (lane >= off) incl += tshf;
        }
        if (lane == 63) iw[w] = incl;
        __syncthreads();
        int woff = 0;
        for (int ww = 0; ww < w; ++ww) woff += iw[ww];
        if (tid < NSBLK) bsum[tid] = woff + incl - v;
    }
    grid.sync();

    // ---- P3: scatter edges to row-sorted slots (atomicSub consumes cnt) ----
    for (int e = gid; e < NE; e += GSTR) {
        int r   = erow[e];
        int p   = atomicSub(&cnt[r], 1) - 1;   // unique slot 0..count-1
        int dst = rs[r] + bsum[r >> 8] + p;
        uint2 cv;
        cv.x = (unsigned)ecol[e];
        cv.y = __builtin_bit_cast(unsigned, ev[e]);
        cv_s[dst] = cv;                        // single 8 B write per edge
    }
}

// ---------------------------------------------------------------------------
// Fallback path (used only if the cooperative launch is refused): the
// R3-proven multi-kernel pipeline, adapted to 256-wide scan blocks so the
// rs/bsum layout matches spmm's bsum[r>>8] indexing.
// ---------------------------------------------------------------------------
__global__ __launch_bounds__(256) void gemm_fb(
    const float* __restrict__ x, const float* __restrict__ W,
    unsigned short* __restrict__ h, const int* __restrict__ erow,
    int* __restrict__ cnt, int M)
{
    __shared__ short wsh[128 * LDW];
    const int tid = threadIdx.x;
    for (int e = blockIdx.x * 256 + tid; e < NE; e += gridDim.x * 256)
        atomicAdd(&cnt[erow[e]], 1);
    stage_W(W, wsh, tid);
    __syncthreads();
    gemm_tile(x, h, wsh, blockIdx.x, M, tid);
}

__global__ __launch_bounds__(256) void scan1_fb(
    const int* __restrict__ cnt, int* __restrict__ rs, int* __restrict__ bsum)
{
    __shared__ int iw[4];
    const int tid  = threadIdx.x;
    const int lane = tid & 63;
    const int w    = tid >> 6;
    int i = blockIdx.x * 256 + tid;
    int v = (i < NN) ? cnt[i] : 0;
    int incl = v;
#pragma unroll
    for (int off = 1; off < 64; off <<= 1) {
        int t = __shfl_up(incl, off, 64);
        if (lane >= off) incl += t;
    }
    if (lane == 63) iw[w] = incl;
    __syncthreads();
    int woff = 0;
    for (int ww = 0; ww < w; ++ww) woff += iw[ww];
    if (i < NN) rs[i] = woff + incl - v;
    if (tid == 255) bsum[blockIdx.x] = woff + incl;
}

__global__ __launch_bounds__(256) void scan2_fb(int* __restrict__ bsum)
{
    __shared__ int iw[4];
    const int tid  = threadIdx.x;
    const int lane = tid & 63;
    const int w    = tid >> 6;
    int v = (tid < NSBLK) ? bsum[tid] : 0;
    int incl = v;
#pragma unroll
    for (int off = 1; off < 64; off <<= 1) {
        int t = __shfl_up(incl, off, 64);
        if (lane >= off) incl += t;
    }
    if (lane == 63) iw[w] = incl;
    __syncthreads();
    int woff = 0;
    for (int ww = 0; ww < w; ++ww) woff += iw[ww];
    if (tid < NSBLK) bsum[tid] = woff + incl - v;
}

__global__ void scatter_fb(const int* __restrict__ row,
                           const int* __restrict__ col,
                           const float* __restrict__ val,
                           const int* __restrict__ rs,
                           const int* __restrict__ bsum,
                           int* __restrict__ cnt,
                           uint2* __restrict__ cv_s)
{
    int e = blockIdx.x * 256 + threadIdx.x;
    if (e < NE) {
        int r   = row[e];
        int p   = atomicSub(&cnt[r], 1) - 1;
        int dst = rs[r] + bsum[r >> 8] + p;
        uint2 cv;
        cv.x = (unsigned)col[e];
        cv.y = __builtin_bit_cast(unsigned, val[e]);
        cv_s[dst] = cv;
    }
}

// ---------------------------------------------------------------------------
// SpMM: wave per output row; coalesced cv preload + readlane broadcast.
// Proven floor (~126 us): R1 restructure null, R4 8-deep pipeline null ->
// throughput wall on the L2-miss/fabric gather path.  4-deep / 28-VGPR body.
// ---------------------------------------------------------------------------
__global__ __launch_bounds__(256) void spmm_kernel(
    const unsigned short* __restrict__ h,   // [NN][NB][NF] bf16
    const int* __restrict__ rs,
    const int* __restrict__ bsum,
    const uint2* __restrict__ cv_s,         // packed (col, val)
    float* __restrict__ out)                // [NB][NN][NF] fp32
{
    const int w    = threadIdx.x >> 6;
    const int lane = threadIdx.x & 63;
    int r = blockIdx.x * 4 + w;
    if (r >= NN) return;
    r = __builtin_amdgcn_readfirstlane(r);  // wave-uniform by construction

    const int s = rs[r] + bsum[r >> 8];
    const int e = (r + 1 == NN) ? NE : rs[r + 1] + bsum[(r + 1) >> 8];
    const int b    = lane >> 4;
    const int loff = b * NF + (lane & 15) * 8;   // element offset within h row

    float acc[8];
#pragma unroll
    for (int k = 0; k < 8; ++k) acc[k] = 0.f;

    for (int base = s; base < e; base += 64) {
        const int n = min(64, e - base);
        // coalesced preload of up to 64 edges; inactive lanes -> (col=0,val=0)
        unsigned long long cvp = 0ull;
        if (lane < n)
            cvp = __builtin_nontemporal_load(
                      (const unsigned long long*)(cv_s + base + lane));
        const int cvx = (int)(unsigned)(cvp & 0xffffffffull);   // col
        const int cvy = (int)(unsigned)(cvp >> 32);             // val bits

        const int n4 = (n + 3) & ~3;   // padded: lanes >= n contribute 0
        for (int i = 0; i < n4; i += 4) {
            const unsigned c0 = (unsigned)__builtin_amdgcn_readlane(cvx, i);
            const unsigned c1 = (unsigned)__builtin_amdgcn_readlane(cvx, i + 1);
            const unsigned c2 = (unsigned)__builtin_amdgcn_readlane(cvx, i + 2);
            const unsigned c3 = (unsigned)__builtin_amdgcn_readlane(cvx, i + 3);
            const uint4 q0 = *(const uint4*)(h + (size_t)c0 * (NB * NF) + loff);
            const uint4 q1 = *(const uint4*)(h + (size_t)c1 * (NB * NF) + loff);
            const uint4 q2 = *(const uint4*)(h + (size_t)c2 * (NB * NF) + loff);
            const uint4 q3 = *(const uint4*)(h + (size_t)c3 * (NB * NF) + loff);
            const float v0 = __builtin_bit_cast(
                float, __builtin_amdgcn_readlane(cvy, i));
            const float v1 = __builtin_bit_cast(
                float, __builtin_amdgcn_readlane(cvy, i + 1));
            const float v2 = __builtin_bit_cast(
                float, __builtin_amdgcn_readlane(cvy, i + 2));
            const float v3 = __builtin_bit_cast(
                float, __builtin_amdgcn_readlane(cvy, i + 3));

            acc[0] += v0 * bflo(q0.x); acc[1] += v0 * bfhi(q0.x);
            acc[2] += v0 * bflo(q0.y); acc[3] += v0 * bfhi(q0.y);
            acc[4] += v0 * bflo(q0.z); acc[5] += v0 * bfhi(q0.z);
            acc[6] += v0 * bflo(q0.w); acc[7] += v0 * bfhi(q0.w);
            acc[0] += v1 * bflo(q1.x); acc[1] += v1 * bfhi(q1.x);
            acc[2] += v1 * bflo(q1.y); acc[3] += v1 * bfhi(q1.y);
            acc[4] += v1 * bflo(q1.z); acc[5] += v1 * bfhi(q1.z);
            acc[6] += v1 * bflo(q1.w); acc[7] += v1 * bfhi(q1.w);
            acc[0] += v2 * bflo(q2.x); acc[1] += v2 * bfhi(q2.x);
            acc[2] += v2 * bflo(q2.y); acc[3] += v2 * bfhi(q2.y);
            acc[4] += v2 * bflo(q2.z); acc[5] += v2 * bfhi(q2.z);
            acc[6] += v2 * bflo(q2.w); acc[7] += v2 * bfhi(q2.w);
            acc[0] += v3 * bflo(q3.x); acc[1] += v3 * bfhi(q3.x);
            acc[2] += v3 * bflo(q3.y); acc[3] += v3 * bfhi(q3.y);
            acc[4] += v3 * bflo(q3.z); acc[5] += v3 * bfhi(q3.z);
            acc[6] += v3 * bflo(q3.w); acc[7] += v3 * bfhi(q3.w);
        }
    }

    float* op = out + ((size_t)b * NN + r) * NF + (lane & 15) * 8;
    *(float4*)op       = make_float4(acc[0], acc[1], acc[2], acc[3]);
    *(float4*)(op + 4) = make_float4(acc[4], acc[5], acc[6], acc[7]);
}

// ---------------------------------------------------------------------------
extern "C" void kernel_launch(void* const* d_in, const int* in_sizes, int n_in,
                              void* d_out, int out_size, void* d_ws, size_t ws_size,
                              hipStream_t stream)
{
    const float* x    = (const float*)d_in[0];
    const float* W    = (const float*)d_in[1];
    const int*   erow = (const int*)d_in[2];
    const int*   ecol = (const int*)d_in[3];
    const float* ev   = (const float*)d_in[4];
    float*       out  = (float*)d_out;

    char*  ws  = (char*)d_ws;
    size_t off = 0;
    auto alloc = [&](size_t bytes) -> void* {
        void* p = ws + off;
        off += (bytes + 255) & ~(size_t)255;
        return p;
    };
    unsigned short* h = (unsigned short*)alloc((size_t)NN * NB * NF * sizeof(unsigned short)); // 51.2 MB
    int*   rs   = (int*)  alloc((size_t)(NN + 1) * sizeof(int));
    int*   cnt  = (int*)  alloc((size_t)NN * sizeof(int));
    int*   bsum = (int*)  alloc((size_t)256 * sizeof(int));
    uint2* cv_s = (uint2*)alloc((size_t)NE * sizeof(uint2));

    const int M = NB * NN;

    void* args[] = {(void*)&x, (void*)&W, (void*)&h, (void*)&erow, (void*)&ecol,
                    (void*)&ev, (void*)&rs, (void*)&cnt, (void*)&bsum, (void*)&cv_s};
    hipError_t cerr = hipLaunchCooperativeKernel((void*)front_kernel, dim3(GRID),
                                                 dim3(NTHR), args, 0, stream);
    if (cerr != hipSuccess) {
        // R3-proven multi-kernel fallback (≈378 µs total path)
        hipMemsetAsync(cnt, 0, (size_t)NN * sizeof(int), stream);
        gemm_fb<<<NTILE, 256, 0, stream>>>(x, W, h, erow, cnt, M);
        scan1_fb<<<NSBLK, 256, 0, stream>>>(cnt, rs, bsum);
        scan2_fb<<<1, 256, 0, stream>>>(bsum);
        scatter_fb<<<(NE + 255) / 256, 256, 0, stream>>>(erow, ecol, ev, rs,
                                                         bsum, cnt, cv_s);
    }

    spmm_kernel<<<(NN + 3) / 4, 256, 0, stream>>>(h, rs, bsum, cv_s, out);
}

// Round 7
// 386.188 us; speedup vs baseline: 1.5376x; 1.5376x over previous
//
#include <hip/hip_runtime.h>
#include <stdint.h>

// Problem constants (fixed by the reference):
#define NB 4
#define NN 50000
#define NE 800000
#define NF 128

#define NSBLK 196            // ceil(NN / 256) scan blocks (256 nodes each)
#define NNP   50176          // NSBLK*256, padded counter stride
#define NCPY  8              // counter privatization factor (copy = e & 7)
#define NTILE 1563           // ceil(NB*NN / 128) GEMM row tiles
#define LDW   136            // W-LDS / epilogue-tile row stride in bf16 (128 + 8 pad)

typedef __attribute__((ext_vector_type(8))) short  bfrag;    // 8 bf16 (4 VGPR)
typedef __attribute__((ext_vector_type(4))) float  ffrag;    // 4 fp32 acc
typedef __attribute__((ext_vector_type(4))) short  short4v;  // 8 B LDS store

// fp32 -> bf16 round-to-nearest-even
__device__ inline unsigned short f2bf(float f) {
    unsigned int u = __builtin_bit_cast(unsigned int, f);
    u += 0x7fffu + ((u >> 16) & 1u);
    return (unsigned short)(u >> 16);
}
__device__ inline float bflo(unsigned int u) { return __builtin_bit_cast(float, u << 16); }
__device__ inline float bfhi(unsigned int u) { return __builtin_bit_cast(float, u & 0xffff0000u); }

// ---------------------------------------------------------------------------
// GEMM (+fused 8-way privatized histogram): h[n][b][o] = bf16(x @ W^T).
// W staged to LDS once per block behind one barrier; x streamed straight from
// global into MFMA fragments (no barriers in the K-loop).  Histogram copy
// index is e&7 (edge-determined, so the scatter pass sees identical per-copy
// counts) -> per-word atomic contention drops 16 -> 2.
// ---------------------------------------------------------------------------
__global__ __launch_bounds__(256) void gemm_kernel(
    const float* __restrict__ x,        // [M][NF] fp32
    const float* __restrict__ W,        // [NF][NF] fp32 (row = out feature)
    unsigned short* __restrict__ h,     // [NN][NB][NF] bf16, node-major
    const int* __restrict__ erow,
    int* __restrict__ cnt8,             // [NCPY][NNP] privatized histogram (zeroed)
    int M)
{
    __shared__ short wsh[128 * LDW];    // 34.8 KB: W bf16, then epilogue tile

    const int tid = threadIdx.x;

    // --- fused histogram (overlaps with W staging + first x loads) ---
    for (int e = blockIdx.x * 256 + tid; e < NE; e += gridDim.x * 256)
        atomicAdd(&cnt8[(e & 7) * NNP + erow[e]], 1);

    // --- stage W -> LDS bf16, once ---
#pragma unroll
    for (int it = 0; it < 16; ++it) {
        int idx = it * 256 + tid;       // float4 slot 0..4095
        int r   = idx >> 5;
        int c4  = idx & 31;
        float4 wv = *(const float4*)(W + (size_t)r * NF + c4 * 4);
        short4v wsv;
        wsv[0] = (short)f2bf(wv.x); wsv[1] = (short)f2bf(wv.y);
        wsv[2] = (short)f2bf(wv.z); wsv[3] = (short)f2bf(wv.w);
        *(short4v*)&wsh[r * LDW + c4 * 4] = wsv;
    }
    __syncthreads();

    const int w    = tid >> 6;
    const int lane = tid & 63;
    const int q    = lane >> 4;
    const int l15  = lane & 15;
    const int r0   = blockIdx.x * 128 + w * 32;

    const float* xp[2];
#pragma unroll
    for (int i = 0; i < 2; ++i) {
        int gr = r0 + i * 16 + l15;
        gr = gr < M ? gr : M - 1;       // clamp: OOB rows computed, never stored
        xp[i] = x + (size_t)gr * NF + q * 8;
    }

    ffrag acc[2][8];
#pragma unroll
    for (int i = 0; i < 2; ++i)
#pragma unroll
        for (int j = 0; j < 8; ++j) acc[i][j] = (ffrag)0.f;

#pragma unroll 2
    for (int kc = 0; kc < 4; ++kc) {    // K-chunks of 32; NO barriers inside
        bfrag a[2];
#pragma unroll
        for (int i = 0; i < 2; ++i) {
            float4 u0 = *(const float4*)(xp[i] + kc * 32);
            float4 u1 = *(const float4*)(xp[i] + kc * 32 + 4);
            bfrag tt;
            tt[0] = (short)f2bf(u0.x); tt[1] = (short)f2bf(u0.y);
            tt[2] = (short)f2bf(u0.z); tt[3] = (short)f2bf(u0.w);
            tt[4] = (short)f2bf(u1.x); tt[5] = (short)f2bf(u1.y);
            tt[6] = (short)f2bf(u1.z); tt[7] = (short)f2bf(u1.w);
            a[i] = tt;
        }
#pragma unroll
        for (int j = 0; j < 8; ++j) {
            bfrag b = *(const bfrag*)&wsh[(j * 16 + l15) * LDW + kc * 32 + q * 8];
            acc[0][j] = __builtin_amdgcn_mfma_f32_16x16x32_bf16(
                a[0], b, acc[0][j], 0, 0, 0);
            acc[1][j] = __builtin_amdgcn_mfma_f32_16x16x32_bf16(
                a[1], b, acc[1][j], 0, 0, 0);
        }
    }

    // --- epilogue: repack through LDS (reuses wsh), coalesced 16 B stores ---
    __syncthreads();
    short* tile = wsh;
#pragma unroll
    for (int i = 0; i < 2; ++i)
#pragma unroll
        for (int reg = 0; reg < 4; ++reg) {
            int row = w * 32 + i * 16 + q * 4 + reg;
#pragma unroll
            for (int j = 0; j < 8; ++j)
                tile[row * LDW + j * 16 + l15] = (short)f2bf(acc[i][j][reg]);
        }
    __syncthreads();
#pragma unroll
    for (int it = 0; it < 8; ++it) {
        int row = it * 16 + (tid >> 4);
        int m   = blockIdx.x * 128 + row;
        if (m < M) {
            int n  = m % NN;
            int bb = m / NN;
            uint4 v = *(const uint4*)&tile[row * LDW + (tid & 15) * 8];
            *(uint4*)(h + ((size_t)n * NB + bb) * NF + (tid & 15) * 8) = v;
        }
    }
}

// ---------------------------------------------------------------------------
// scan1: per-node total over the 8 copies, coalesced block-exclusive scan.
// rs[i] gets the BLOCK-LOCAL exclusive offset; bsum[b] the block total.
// ---------------------------------------------------------------------------
__global__ __launch_bounds__(256) void scan1_kernel(
    const int* __restrict__ cnt8, int* __restrict__ rs, int* __restrict__ bsum)
{
    __shared__ int iw[4];
    const int tid  = threadIdx.x;
    const int lane = tid & 63;
    const int w    = tid >> 6;
    const int i    = blockIdx.x * 256 + tid;

    int v = 0;
    if (i < NN)
#pragma unroll
        for (int c = 0; c < NCPY; ++c) v += cnt8[c * NNP + i];

    int incl = v;
#pragma unroll
    for (int off = 1; off < 64; off <<= 1) {
        int t = __shfl_up(incl, off, 64);
        if (lane >= off) incl += t;
    }
    if (lane == 63) iw[w] = incl;
    __syncthreads();
    int woff = 0;
    for (int ww = 0; ww < w; ++ww) woff += iw[ww];
    if (i < NN) rs[i] = woff + incl - v;
    if (tid == 255) bsum[blockIdx.x] = woff + incl;
}

// ---------------------------------------------------------------------------
// scan2: exclusive scan of the 196 block sums (one 256-thread block).
// ---------------------------------------------------------------------------
__global__ __launch_bounds__(256) void scan2_kernel(int* __restrict__ bsum)
{
    __shared__ int iw[4];
    const int tid  = threadIdx.x;
    const int lane = tid & 63;
    const int w    = tid >> 6;
    int v = (tid < NSBLK) ? bsum[tid] : 0;
    int incl = v;
#pragma unroll
    for (int off = 1; off < 64; off <<= 1) {
        int t = __shfl_up(incl, off, 64);
        if (lane >= off) incl += t;
    }
    if (lane == 63) iw[w] = incl;
    __syncthreads();
    int woff = 0;
    for (int ww = 0; ww < w; ++ww) woff += iw[ww];
    if (tid < NSBLK) bsum[tid] = woff + incl - v;
}

// ---------------------------------------------------------------------------
// scan3: finalize rs in place (add block offset) and convert cnt8 into
// per-copy segment-END cursors (inclusive prefix over copies).  After this,
// scatter needs NO rs/bsum reads at all.
// ---------------------------------------------------------------------------
__global__ __launch_bounds__(256) void scan3_kernel(
    int* __restrict__ rs, const int* __restrict__ bsum, int* __restrict__ cnt8)
{
    const int i = blockIdx.x * 256 + threadIdx.x;
    if (i < NN) {
        int run = rs[i] + bsum[i >> 8];
        rs[i] = run;
#pragma unroll
        for (int c = 0; c < NCPY; ++c) {
            run += cnt8[c * NNP + i];
            cnt8[c * NNP + i] = run;      // end offset of copy c's segment
        }
    }
    if (i == 0) rs[NN] = NE;
}

// ---------------------------------------------------------------------------
// Scatter: dst comes straight from the privatized cursor (atomicSub counts
// the segment down).  3 loads + 1 atomic (contention /8) + 1 store per edge.
// ---------------------------------------------------------------------------
__global__ void scatter_kernel(const int* __restrict__ row,
                               const int* __restrict__ col,
                               const float* __restrict__ val,
                               int* __restrict__ cur8,
                               uint2* __restrict__ cv_s)
{
    int e = blockIdx.x * 256 + threadIdx.x;
    if (e < NE) {
        int r = row[e];
        int p = atomicSub(&cur8[(e & 7) * NNP + r], 1) - 1;
        uint2 cv;
        cv.x = (unsigned)col[e];
        cv.y = __builtin_bit_cast(unsigned, val[e]);
        cv_s[p] = cv;                      // single 8 B write per edge
    }
}

// ---------------------------------------------------------------------------
// SpMM: wave per output row; coalesced cv preload + readlane broadcast.
// Proven floor (~126 us): R1 restructure null, R4 8-deep pipeline null ->
// throughput wall on the L2-miss/fabric gather path.  4-deep / 28-VGPR body.
// ---------------------------------------------------------------------------
__global__ __launch_bounds__(256) void spmm_kernel(
    const unsigned short* __restrict__ h,   // [NN][NB][NF] bf16
    const int* __restrict__ rs,             // final CSR offsets (rs[NN]=NE)
    const uint2* __restrict__ cv_s,         // packed (col, val)
    float* __restrict__ out)                // [NB][NN][NF] fp32
{
    const int w    = threadIdx.x >> 6;
    const int lane = threadIdx.x & 63;
    int r = blockIdx.x * 4 + w;
    if (r >= NN) return;
    r = __builtin_amdgcn_readfirstlane(r);  // wave-uniform by construction

    const int s = rs[r];
    const int e = rs[r + 1];
    const int b    = lane >> 4;
    const int loff = b * NF + (lane & 15) * 8;   // element offset within h row

    float acc[8];
#pragma unroll
    for (int k = 0; k < 8; ++k) acc[k] = 0.f;

    for (int base = s; base < e; base += 64) {
        const int n = min(64, e - base);
        // coalesced preload of up to 64 edges; inactive lanes -> (col=0,val=0)
        unsigned long long cvp = 0ull;
        if (lane < n)
            cvp = __builtin_nontemporal_load(
                      (const unsigned long long*)(cv_s + base + lane));
        const int cvx = (int)(unsigned)(cvp & 0xffffffffull);   // col
        const int cvy = (int)(unsigned)(cvp >> 32);             // val bits

        const int n4 = (n + 3) & ~3;   // padded: lanes >= n contribute 0
        for (int i = 0; i < n4; i += 4) {
            const unsigned c0 = (unsigned)__builtin_amdgcn_readlane(cvx, i);
            const unsigned c1 = (unsigned)__builtin_amdgcn_readlane(cvx, i + 1);
            const unsigned c2 = (unsigned)__builtin_amdgcn_readlane(cvx, i + 2);
            const unsigned c3 = (unsigned)__builtin_amdgcn_readlane(cvx, i + 3);
            const uint4 q0 = *(const uint4*)(h + (size_t)c0 * (NB * NF) + loff);
            const uint4 q1 = *(const uint4*)(h + (size_t)c1 * (NB * NF) + loff);
            const uint4 q2 = *(const uint4*)(h + (size_t)c2 * (NB * NF) + loff);
            const uint4 q3 = *(const uint4*)(h + (size_t)c3 * (NB * NF) + loff);
            const float v0 = __builtin_bit_cast(
                float, __builtin_amdgcn_readlane(cvy, i));
            const float v1 = __builtin_bit_cast(
                float, __builtin_amdgcn_readlane(cvy, i + 1));
            const float v2 = __builtin_bit_cast(
                float, __builtin_amdgcn_readlane(cvy, i + 2));
            const float v3 = __builtin_bit_cast(
                float, __builtin_amdgcn_readlane(cvy, i + 3));

            acc[0] += v0 * bflo(q0.x); acc[1] += v0 * bfhi(q0.x);
            acc[2] += v0 * bflo(q0.y); acc[3] += v0 * bfhi(q0.y);
            acc[4] += v0 * bflo(q0.z); acc[5] += v0 * bfhi(q0.z);
            acc[6] += v0 * bflo(q0.w); acc[7] += v0 * bfhi(q0.w);
            acc[0] += v1 * bflo(q1.x); acc[1] += v1 * bfhi(q1.x);
            acc[2] += v1 * bflo(q1.y); acc[3] += v1 * bfhi(q1.y);
            acc[4] += v1 * bflo(q1.z); acc[5] += v1 * bfhi(q1.z);
            acc[6] += v1 * bflo(q1.w); acc[7] += v1 * bfhi(q1.w);
            acc[0] += v2 * bflo(q2.x); acc[1] += v2 * bfhi(q2.x);
            acc[2] += v2 * bflo(q2.y); acc[3] += v2 * bfhi(q2.y);
            acc[4] += v2 * bflo(q2.z); acc[5] += v2 * bfhi(q2.z);
            acc[6] += v2 * bflo(q2.w); acc[7] += v2 * bfhi(q2.w);
            acc[0] += v3 * bflo(q3.x); acc[1] += v3 * bfhi(q3.x);
            acc[2] += v3 * bflo(q3.y); acc[3] += v3 * bfhi(q3.y);
            acc[4] += v3 * bflo(q3.z); acc[5] += v3 * bfhi(q3.z);
            acc[6] += v3 * bflo(q3.w); acc[7] += v3 * bfhi(q3.w);
        }
    }

    float* op = out + ((size_t)b * NN + r) * NF + (lane & 15) * 8;
    *(float4*)op       = make_float4(acc[0], acc[1], acc[2], acc[3]);
    *(float4*)(op + 4) = make_float4(acc[4], acc[5], acc[6], acc[7]);
}

// ---------------------------------------------------------------------------
extern "C" void kernel_launch(void* const* d_in, const int* in_sizes, int n_in,
                              void* d_out, int out_size, void* d_ws, size_t ws_size,
                              hipStream_t stream)
{
    const float* x    = (const float*)d_in[0];
    const float* W    = (const float*)d_in[1];
    const int*   erow = (const int*)d_in[2];
    const int*   ecol = (const int*)d_in[3];
    const float* ev   = (const float*)d_in[4];
    float*       out  = (float*)d_out;

    char*  ws  = (char*)d_ws;
    size_t off = 0;
    auto alloc = [&](size_t bytes) -> void* {
        void* p = ws + off;
        off += (bytes + 255) & ~(size_t)255;
        return p;
    };
    unsigned short* h = (unsigned short*)alloc((size_t)NN * NB * NF * sizeof(unsigned short)); // 51.2 MB
    int*   rs   = (int*)  alloc((size_t)(NN + 1) * sizeof(int));
    int*   cnt8 = (int*)  alloc((size_t)NCPY * NNP * sizeof(int));   // 1.6 MB
    int*   bsum = (int*)  alloc((size_t)256 * sizeof(int));
    uint2* cv_s = (uint2*)alloc((size_t)NE * sizeof(uint2));

    hipMemsetAsync(cnt8, 0, (size_t)NCPY * NNP * sizeof(int), stream);

    const int M = NB * NN;
    gemm_kernel<<<NTILE, 256, 0, stream>>>(x, W, h, erow, cnt8, M);

    scan1_kernel<<<NSBLK, 256, 0, stream>>>(cnt8, rs, bsum);
    scan2_kernel<<<1, 256, 0, stream>>>(bsum);
    scan3_kernel<<<NSBLK, 256, 0, stream>>>(rs, bsum, cnt8);
    scatter_kernel<<<(NE + 255) / 256, 256, 0, stream>>>(erow, ecol, ev,
                                                         cnt8, cv_s);

    spmm_kernel<<<(NN + 3) / 4, 256, 0, stream>>>(h, rs, cv_s, out);
}